// Round 3
// baseline (363.941 us; speedup 1.0000x reference)
//
#include <hip/hip_runtime.h>
#include <math.h>

// Shape: B=2 C=8 N=16384 D=256 H=W=64 ; rows = B*N = 32768
#define NROWS 32768

typedef __attribute__((ext_vector_type(8))) short short8;
typedef __attribute__((ext_vector_type(4))) float f32x4;

// Workspace layout (units of float):
//  ABF    ushort[65536]  A^T in MFMA-B-fragment order (see fragidx)
//  WVOF   ushort[65536]  Wvo^T in MFMA-B-fragment order
//  PB     float[256]     bq @ Wk^T
//  BVO    float[256]     bv @ Wo
//  SUMA   float[32768]   1.0 if any valid context else 0.0
//  P      ushort[32768*256] p = (LN(q)@A + pb)/16, bf16; overwritten by sbar bf16
//  FEATBF ushort[16*1048576] bf16 copy of image_features
#define WS_ABF    0
#define WS_WVOF   32768
#define WS_PB     65536
#define WS_BVO    65792
#define WS_SUMA   66048
#define WS_P      98816
#define WS_FEATBF 4293120
// total = 12,681,728 floats = 50.7 MB

__device__ __forceinline__ unsigned short f2bf(float f) {
    unsigned u = __builtin_bit_cast(unsigned, f);
    u += 0x7FFFu + ((u >> 16) & 1u);          // RNE
    return (unsigned short)(u >> 16);
}
__device__ __forceinline__ float bf_lo(unsigned u) {
    return __builtin_bit_cast(float, u << 16);
}
__device__ __forceinline__ float bf_hi(unsigned u) {
    return __builtin_bit_cast(float, u & 0xFFFF0000u);
}
// B-fragment swizzle: element (outcol, k) of a [256 outcols][256 k] matrix
// lives at frag index so a wave's 16B/lane load is contiguous:
//   ct=outcol>>4, r16=outcol&15, ks=k>>5, g=(k>>3)&3, j=k&7
//   idx = (((ct*8+ks)*64) + g*16 + r16)*8 + j
__device__ __forceinline__ int fragidx(int outcol, int k) {
    int ct = outcol >> 4, r16 = outcol & 15;
    int ks = k >> 5, g = (k >> 3) & 3, j = k & 7;
    return ((((ct << 3) + ks) << 6) + (g << 4) + r16) * 8 + j;
}

// ---------------- precompute: A^T(frag), Wvo^T(frag), pb, bvo, feat->bf16 -------------
__global__ __launch_bounds__(256)
void precompute_kernel(const float* __restrict__ Wq, const float* __restrict__ bq,
                       const float* __restrict__ Wkv, const float* __restrict__ bkv,
                       const float* __restrict__ Wo, const float* __restrict__ feat,
                       float* __restrict__ ws) {
    int t = threadIdx.x;
    int blk = blockIdx.x;
    if (blk >= 514) {
        // feature map fp32 -> bf16, 1024 elems per block
        long i = (long)(blk - 514) * 1024 + t * 4;
        float4 v = *(const float4*)(feat + i);
        unsigned lo = (unsigned)f2bf(v.x) | ((unsigned)f2bf(v.y) << 16);
        unsigned hi = (unsigned)f2bf(v.z) | ((unsigned)f2bf(v.w) << 16);
        *(uint2*)((unsigned short*)(ws + WS_FEATBF) + i) = make_uint2(lo, hi);
        return;
    }
    if (blk < 256) {
        // A^T[e][f] = Wq[f,:] . Wk[e,:] ;  f = blk, e = t  (outcol=e, k=f)
        int f = blk;
        const float4* wq4 = (const float4*)(Wq + f * 256);
        const float4* wk4 = (const float4*)(Wkv + (long)t * 512);
        float acc = 0.f;
        #pragma unroll 8
        for (int d4 = 0; d4 < 64; ++d4) {
            float4 a = wq4[d4], b = wk4[d4];
            acc += a.x * b.x + a.y * b.y + a.z * b.z + a.w * b.w;
        }
        ((unsigned short*)(ws + WS_ABF))[fragidx(t, f)] = f2bf(acc);
    } else if (blk < 512) {
        // Wvo^T[d][e] = sum_g Wv[e,g]*Wo[g,d] ;  e = blk-256, d = t (outcol=d, k=e)
        int e = blk - 256;
        float acc = 0.f;
        #pragma unroll 8
        for (int g = 0; g < 256; ++g)
            acc = fmaf(Wkv[(long)e * 512 + 256 + g], Wo[g * 256 + t], acc);
        ((unsigned short*)(ws + WS_WVOF))[fragidx(t, e)] = f2bf(acc);
    } else if (blk == 512) {
        float acc = 0.f;
        #pragma unroll 8
        for (int d = 0; d < 256; ++d)
            acc = fmaf(bq[d], Wkv[(long)t * 512 + d], acc);
        ws[WS_PB + t] = acc;
    } else {
        float acc = 0.f;
        #pragma unroll 8
        for (int g = 0; g < 256; ++g)
            acc = fmaf(bkv[256 + g], Wo[g * 256 + t], acc);
        ws[WS_BVO + t] = acc;
    }
}

// ---------------- fused layernorm + p = (LN(q)@A + pb)/16  (bf16 MFMA, bf16 out) ------
// 64 rows per block, 4 waves; wave w owns output columns [64w, 64w+64)
__global__ __launch_bounds__(256)
void ln_p_mfma(const float* __restrict__ queries, const float* __restrict__ gamma,
               const float* __restrict__ beta, float* __restrict__ ws) {
    __shared__ unsigned short qs[64][264];   // bf16 LN(q) tile; reused for p repack
    const unsigned short* Afrag = (const unsigned short*)(ws + WS_ABF);
    const float* pb = ws + WS_PB;
    unsigned short* pbf = (unsigned short*)(ws + WS_P);
    int tid = threadIdx.x, wave = tid >> 6, lane = tid & 63;
    long row0 = (long)blockIdx.x * 64;

    float4 g4 = *(const float4*)(gamma + 4 * lane);
    float4 b4 = *(const float4*)(beta + 4 * lane);
    for (int rr = 0; rr < 16; ++rr) {
        int r = wave * 16 + rr;
        float4 v = *(const float4*)(queries + (row0 + r) * 256 + 4 * lane);
        float s = v.x + v.y + v.z + v.w;
        s += __shfl_xor(s, 32); s += __shfl_xor(s, 16); s += __shfl_xor(s, 8);
        s += __shfl_xor(s, 4);  s += __shfl_xor(s, 2);  s += __shfl_xor(s, 1);
        float mu = s * 0.00390625f;
        float dx = v.x - mu, dy = v.y - mu, dz = v.z - mu, dw = v.w - mu;
        float vv = dx * dx + dy * dy + dz * dz + dw * dw;
        vv += __shfl_xor(vv, 32); vv += __shfl_xor(vv, 16); vv += __shfl_xor(vv, 8);
        vv += __shfl_xor(vv, 4);  vv += __shfl_xor(vv, 2);  vv += __shfl_xor(vv, 1);
        float rstd = rsqrtf(vv * 0.00390625f + 1e-5f);
        float qx = dx * rstd * g4.x + b4.x;
        float qy = dy * rstd * g4.y + b4.y;
        float qz = dz * rstd * g4.z + b4.z;
        float qw = dw * rstd * g4.w + b4.w;
        unsigned lo = (unsigned)f2bf(qx) | ((unsigned)f2bf(qy) << 16);
        unsigned hi = (unsigned)f2bf(qz) | ((unsigned)f2bf(qw) << 16);
        *(uint2*)&qs[r][4 * lane] = make_uint2(lo, hi);
    }
    __syncthreads();

    int r16 = lane & 15, g = lane >> 4;
    f32x4 zero = {0.f, 0.f, 0.f, 0.f};
    f32x4 acc[4][4];
    #pragma unroll
    for (int mt = 0; mt < 4; ++mt)
        #pragma unroll
        for (int nt = 0; nt < 4; ++nt) acc[mt][nt] = zero;

    #pragma unroll
    for (int ks = 0; ks < 8; ++ks) {
        short8 bfr[4], afr[4];
        #pragma unroll
        for (int nt = 0; nt < 4; ++nt)
            bfr[nt] = *(const short8*)(Afrag + (((((wave * 4 + nt) << 3) + ks) << 6) + lane) * 8);
        #pragma unroll
        for (int mt = 0; mt < 4; ++mt)
            afr[mt] = *(const short8*)(&qs[mt * 16 + r16][ks * 32 + g * 8]);
        #pragma unroll
        for (int mt = 0; mt < 4; ++mt)
            #pragma unroll
            for (int nt = 0; nt < 4; ++nt)
                acc[mt][nt] = __builtin_amdgcn_mfma_f32_16x16x32_bf16(afr[mt], bfr[nt], acc[mt][nt], 0, 0, 0);
    }
    __syncthreads();   // done reading qs (A-frags) before repacking p into it

    float pbv[4];
    #pragma unroll
    for (int nt = 0; nt < 4; ++nt) pbv[nt] = pb[wave * 64 + nt * 16 + r16];
    #pragma unroll
    for (int mt = 0; mt < 4; ++mt)
        #pragma unroll
        for (int nt = 0; nt < 4; ++nt)
            #pragma unroll
            for (int rg = 0; rg < 4; ++rg)
                qs[mt * 16 + g * 4 + rg][wave * 64 + nt * 16 + r16] =
                    f2bf((acc[mt][nt][rg] + pbv[nt]) * 0.0625f);
    __syncthreads();

    for (int rr = 0; rr < 16; ++rr) {
        int r = wave * 16 + rr;
        uint2 v = *(const uint2*)&qs[r][4 * lane];
        *(uint2*)(pbf + ((row0 + r) << 8) + 4 * lane) = v;
    }
}

// ---------------- sample + score + softmax + weighted sum ----------------------------
// 2 rows per wave (half-wave of 32 lanes each, 8 dims/lane); sbar bf16 in-place over p
__global__ __launch_bounds__(256)
void sample_attn2(const float* __restrict__ coords, const int* __restrict__ vmask,
                  float* __restrict__ ws) {
    unsigned short* pbf = (unsigned short*)(ws + WS_P);
    float* suma = ws + WS_SUMA;
    const unsigned short* featbf = (const unsigned short*)(ws + WS_FEATBF);
    int tid = threadIdx.x, wave = tid >> 6, lane = tid & 63;
    int h = lane >> 5, l5 = lane & 31;
    long row = (long)blockIdx.x * 8 + wave * 2 + h;
    int b = (int)(row >> 14);
    int n = (int)(row & 16383);

    uint4 pv = *(const uint4*)(pbf + (row << 8) + (l5 << 3));
    float p8[8];
    p8[0] = bf_lo(pv.x); p8[1] = bf_hi(pv.x);
    p8[2] = bf_lo(pv.y); p8[3] = bf_hi(pv.y);
    p8[4] = bf_lo(pv.z); p8[5] = bf_hi(pv.z);
    p8[6] = bf_lo(pv.w); p8[7] = bf_hi(pv.w);

    float sc[8][8];
    float score[8];
    bool vld[8];
    #pragma unroll
    for (int c = 0; c < 8; ++c) {
        long cb = ((long)(b * 8 + c) << 14) + n;
        float2 cxy = *(const float2*)(coords + 2 * cb);
        vld[c] = (vmask[cb] != 0);
        float x = (cxy.x + 1.f) * 31.5f;
        float y = (cxy.y + 1.f) * 31.5f;
        float x0f = floorf(x), y0f = floorf(y);
        float wx = x - x0f, wy = y - y0f;
        int ix0 = (int)x0f, iy0 = (int)y0f;
        int ix1 = ix0 + 1, iy1 = iy0 + 1;
        float bx0 = (ix0 >= 0 && ix0 < 64) ? 1.f : 0.f;
        float bx1 = (ix1 >= 0 && ix1 < 64) ? 1.f : 0.f;
        float by0 = (iy0 >= 0 && iy0 < 64) ? 1.f : 0.f;
        float by1 = (iy1 >= 0 && iy1 < 64) ? 1.f : 0.f;
        int cx0 = min(max(ix0, 0), 63), cx1 = min(max(ix1, 0), 63);
        int cy0 = min(max(iy0, 0), 63), cy1 = min(max(iy1, 0), 63);
        const unsigned short* fb = featbf + ((long)(b * 8 + c) << 20);
        float w00 = (1.f - wy) * (1.f - wx) * by0 * bx0;
        float w01 = (1.f - wy) * wx * by0 * bx1;
        float w10 = wy * (1.f - wx) * by1 * bx0;
        float w11 = wy * wx * by1 * bx1;
        uint4 v00 = *(const uint4*)(fb + ((cy0 * 64 + cx0) << 8) + (l5 << 3));
        uint4 v01 = *(const uint4*)(fb + ((cy0 * 64 + cx1) << 8) + (l5 << 3));
        uint4 v10 = *(const uint4*)(fb + ((cy1 * 64 + cx0) << 8) + (l5 << 3));
        uint4 v11 = *(const uint4*)(fb + ((cy1 * 64 + cx1) << 8) + (l5 << 3));
        float t0 = 0.f, t1 = 0.f;
        #pragma unroll
        for (int j = 0; j < 4; ++j) {
            unsigned u00 = (&v00.x)[j], u01 = (&v01.x)[j], u10 = (&v10.x)[j], u11 = (&v11.x)[j];
            float e0 = w00 * bf_lo(u00) + w01 * bf_lo(u01) + w10 * bf_lo(u10) + w11 * bf_lo(u11);
            float e1 = w00 * bf_hi(u00) + w01 * bf_hi(u01) + w10 * bf_hi(u10) + w11 * bf_hi(u11);
            sc[c][2 * j] = e0;
            sc[c][2 * j + 1] = e1;
            t0 = fmaf(e0, p8[2 * j], t0);
            t1 = fmaf(e1, p8[2 * j + 1], t1);
        }
        float t = t0 + t1;
        t += __shfl_xor(t, 16); t += __shfl_xor(t, 8);
        t += __shfl_xor(t, 4);  t += __shfl_xor(t, 2);  t += __shfl_xor(t, 1);
        score[c] = t;            // 1/sqrt(D) pre-folded into p
    }

    float m = -INFINITY;
    #pragma unroll
    for (int c = 0; c < 8; ++c) if (vld[c]) m = fmaxf(m, score[c]);
    float o8[8];
    #pragma unroll
    for (int j = 0; j < 8; ++j) o8[j] = 0.f;
    float sa = 0.f;
    if (m > -INFINITY) {
        float w[8], s = 0.f;
        #pragma unroll
        for (int c = 0; c < 8; ++c) { w[c] = vld[c] ? __expf(score[c] - m) : 0.f; s += w[c]; }
        float inv = 1.f / s;
        #pragma unroll
        for (int c = 0; c < 8; ++c) {
            float a = w[c] * inv;
            #pragma unroll
            for (int j = 0; j < 8; ++j)
                o8[j] = fmaf(a, sc[c][j], o8[j]);
        }
        sa = 1.f;
    }
    uint4 pk;
    pk.x = (unsigned)f2bf(o8[0]) | ((unsigned)f2bf(o8[1]) << 16);
    pk.y = (unsigned)f2bf(o8[2]) | ((unsigned)f2bf(o8[3]) << 16);
    pk.z = (unsigned)f2bf(o8[4]) | ((unsigned)f2bf(o8[5]) << 16);
    pk.w = (unsigned)f2bf(o8[6]) | ((unsigned)f2bf(o8[7]) << 16);
    *(uint4*)(pbf + (row << 8) + (l5 << 3)) = pk;
    if (l5 == 0) suma[row] = sa;
}

// ---------------- out = residual + sbar@Wvo + suma*bvo + bo  (bf16 MFMA) --------------
__global__ __launch_bounds__(256)
void final_mfma(const float* __restrict__ queries, const float* __restrict__ bo,
                const float* __restrict__ ws, float* __restrict__ out) {
    __shared__ unsigned short qs[64][264];
    __shared__ float ssu[64];
    const unsigned short* Wfrag = (const unsigned short*)(ws + WS_WVOF);
    const float* bvo = ws + WS_BVO;
    const float* suma = ws + WS_SUMA;
    const unsigned short* pbf = (const unsigned short*)(ws + WS_P);
    int tid = threadIdx.x, wave = tid >> 6, lane = tid & 63;
    long row0 = (long)blockIdx.x * 64;

    for (int rr = 0; rr < 16; ++rr) {
        int r = wave * 16 + rr;
        uint2 v = *(const uint2*)(pbf + ((row0 + r) << 8) + 4 * lane);
        *(uint2*)&qs[r][4 * lane] = v;
    }
    if (tid < 64) ssu[tid] = suma[row0 + tid];
    __syncthreads();

    int r16 = lane & 15, g = lane >> 4;
    f32x4 zero = {0.f, 0.f, 0.f, 0.f};
    f32x4 acc[4][4];
    #pragma unroll
    for (int mt = 0; mt < 4; ++mt)
        #pragma unroll
        for (int nt = 0; nt < 4; ++nt) acc[mt][nt] = zero;

    #pragma unroll
    for (int ks = 0; ks < 8; ++ks) {
        short8 bfr[4], afr[4];
        #pragma unroll
        for (int nt = 0; nt < 4; ++nt)
            bfr[nt] = *(const short8*)(Wfrag + (((((wave * 4 + nt) << 3) + ks) << 6) + lane) * 8);
        #pragma unroll
        for (int mt = 0; mt < 4; ++mt)
            afr[mt] = *(const short8*)(&qs[mt * 16 + r16][ks * 32 + g * 8]);
        #pragma unroll
        for (int mt = 0; mt < 4; ++mt)
            #pragma unroll
            for (int nt = 0; nt < 4; ++nt)
                acc[mt][nt] = __builtin_amdgcn_mfma_f32_16x16x32_bf16(afr[mt], bfr[nt], acc[mt][nt], 0, 0, 0);
    }

    float bvov[4], bov[4];
    #pragma unroll
    for (int nt = 0; nt < 4; ++nt) {
        int col = wave * 64 + nt * 16 + r16;
        bvov[nt] = bvo[col];
        bov[nt] = bo[col];
    }
    #pragma unroll
    for (int mt = 0; mt < 4; ++mt)
        #pragma unroll
        for (int nt = 0; nt < 4; ++nt)
            #pragma unroll
            for (int rg = 0; rg < 4; ++rg) {
                long row = row0 + mt * 16 + g * 4 + rg;
                int col = wave * 64 + nt * 16 + r16;
                out[row * 256 + col] = queries[row * 256 + col] + acc[mt][nt][rg]
                                     + ssu[mt * 16 + g * 4 + rg] * bvov[nt] + bov[nt];
            }
}

extern "C" void kernel_launch(void* const* d_in, const int* in_sizes, int n_in,
                              void* d_out, int out_size, void* d_ws, size_t ws_size,
                              hipStream_t stream) {
    const float* queries = (const float*)d_in[0];
    const float* feat    = (const float*)d_in[1];
    const float* coords  = (const float*)d_in[2];
    const int*   vmask   = (const int*)  d_in[3];
    const float* Wq      = (const float*)d_in[4];
    const float* bq      = (const float*)d_in[5];
    const float* Wkv     = (const float*)d_in[6];
    const float* bkv     = (const float*)d_in[7];
    const float* Wo      = (const float*)d_in[8];
    const float* bo      = (const float*)d_in[9];
    const float* gamma   = (const float*)d_in[10];
    const float* beta    = (const float*)d_in[11];
    float* out = (float*)d_out;
    float* ws  = (float*)d_ws;

    precompute_kernel<<<514 + 16384, 256, 0, stream>>>(Wq, bq, Wkv, bkv, Wo, feat, ws);
    ln_p_mfma<<<NROWS / 64, 256, 0, stream>>>(queries, gamma, beta, ws);
    sample_attn2<<<NROWS / 8, 256, 0, stream>>>(coords, vmask, ws);
    final_mfma<<<NROWS / 64, 256, 0, stream>>>(queries, bo, ws, out);
}

// Round 5
// 280.945 us; speedup vs baseline: 1.2954x; 1.2954x over previous
//
#include <hip/hip_runtime.h>
#include <math.h>

// Shape: B=2 C=8 N=16384 D=256 H=W=64 ; rows = B*N = 32768
#define NROWS 32768

typedef __attribute__((ext_vector_type(8))) short short8;
typedef __attribute__((ext_vector_type(4))) float f32x4;
typedef __attribute__((ext_vector_type(4))) unsigned int u32x4;

// Workspace layout (units of float):
//  ABF    ushort[65536]  A^T in MFMA-B-fragment order (see fragidx)
//  WVOF   ushort[65536]  Wvo^T in MFMA-B-fragment order
//  PB     float[256]     bq @ Wk^T
//  BVO    float[256]     bv @ Wo
//  SUMA   float[32768]   1.0 if any valid context else 0.0
//  P      ushort[32768*256] p = (LN(q)@A + pb)/16, bf16; overwritten by sbar bf16
//  FEATBF ushort[16*1048576] bf16 copy of image_features
#define WS_ABF    0
#define WS_WVOF   32768
#define WS_PB     65536
#define WS_BVO    65792
#define WS_SUMA   66048
#define WS_P      98816
#define WS_FEATBF 4293120
// total = 12,681,728 floats = 50.7 MB

__device__ __forceinline__ unsigned short f2bf(float f) {
    unsigned u = __builtin_bit_cast(unsigned, f);
    u += 0x7FFFu + ((u >> 16) & 1u);          // RNE
    return (unsigned short)(u >> 16);
}
__device__ __forceinline__ unsigned short f2bf_u(unsigned u) {
    u += 0x7FFFu + ((u >> 16) & 1u);
    return (unsigned short)(u >> 16);
}
__device__ __forceinline__ unsigned pack_bf2(unsigned lo_bits, unsigned hi_bits) {
    return (unsigned)f2bf_u(lo_bits) | ((unsigned)f2bf_u(hi_bits) << 16);
}
__device__ __forceinline__ float bf_lo(unsigned u) {
    return __builtin_bit_cast(float, u << 16);
}
__device__ __forceinline__ float bf_hi(unsigned u) {
    return __builtin_bit_cast(float, u & 0xFFFF0000u);
}
// B-fragment swizzle: element (outcol, k) of a [256 outcols][256 k] matrix
// stored so a wave's 16B/lane frag load is one contiguous 1KB transaction:
//   ct=outcol>>4, r16=outcol&15, ks=k>>5, g=(k>>3)&3, j=k&7
//   idx = (((ct*8+ks)*64) + g*16 + r16)*8 + j
__device__ __forceinline__ int fragidx(int outcol, int k) {
    int ct = outcol >> 4, r16 = outcol & 15;
    int ks = k >> 5, g = (k >> 3) & 3, j = k & 7;
    return ((((ct << 3) + ks) << 6) + (g << 4) + r16) * 8 + j;
}

// ---------------- precompute: A^T(frag), Wvo^T(frag), pb, bvo, feat->bf16 -------------
// blocks [514, 4610): feature conversion, 16 floats/thread, nontemporal
__global__ __launch_bounds__(256)
void precompute_kernel(const float* __restrict__ Wq, const float* __restrict__ bq,
                       const float* __restrict__ Wkv, const float* __restrict__ bkv,
                       const float* __restrict__ Wo, const float* __restrict__ feat,
                       float* __restrict__ ws) {
    int t = threadIdx.x;
    int blk = blockIdx.x;
    if (blk >= 514) {
        long i = (long)(blk - 514) * 4096 + (long)t * 16;
        const u32x4* src = (const u32x4*)(feat + i);
        u32x4 v0 = __builtin_nontemporal_load(src);
        u32x4 v1 = __builtin_nontemporal_load(src + 1);
        u32x4 v2 = __builtin_nontemporal_load(src + 2);
        u32x4 v3 = __builtin_nontemporal_load(src + 3);
        u32x4 o0, o1;
        o0.x = pack_bf2(v0.x, v0.y); o0.y = pack_bf2(v0.z, v0.w);
        o0.z = pack_bf2(v1.x, v1.y); o0.w = pack_bf2(v1.z, v1.w);
        o1.x = pack_bf2(v2.x, v2.y); o1.y = pack_bf2(v2.z, v2.w);
        o1.z = pack_bf2(v3.x, v3.y); o1.w = pack_bf2(v3.z, v3.w);
        u32x4* dst = (u32x4*)((unsigned short*)(ws + WS_FEATBF) + i);
        __builtin_nontemporal_store(o0, dst);
        __builtin_nontemporal_store(o1, dst + 1);
        return;
    }
    if (blk < 256) {
        // A^T[e][f] = Wq[f,:] . Wk[e,:] ;  f = blk, e = t  (outcol=e, k=f)
        int f = blk;
        const float4* wq4 = (const float4*)(Wq + f * 256);
        const float4* wk4 = (const float4*)(Wkv + (long)t * 512);
        float acc = 0.f;
        #pragma unroll 8
        for (int d4 = 0; d4 < 64; ++d4) {
            float4 a = wq4[d4], b = wk4[d4];
            acc += a.x * b.x + a.y * b.y + a.z * b.z + a.w * b.w;
        }
        ((unsigned short*)(ws + WS_ABF))[fragidx(t, f)] = f2bf(acc);
    } else if (blk < 512) {
        // Wvo^T[d][e] = sum_g Wv[e,g]*Wo[g,d] ;  e = blk-256, d = t (outcol=d, k=e)
        int e = blk - 256;
        float acc = 0.f;
        #pragma unroll 8
        for (int g = 0; g < 256; ++g)
            acc = fmaf(Wkv[(long)e * 512 + 256 + g], Wo[g * 256 + t], acc);
        ((unsigned short*)(ws + WS_WVOF))[fragidx(t, e)] = f2bf(acc);
    } else if (blk == 512) {
        float acc = 0.f;
        #pragma unroll 8
        for (int d = 0; d < 256; ++d)
            acc = fmaf(bq[d], Wkv[(long)t * 512 + d], acc);
        ws[WS_PB + t] = acc;
    } else {
        float acc = 0.f;
        #pragma unroll 8
        for (int g = 0; g < 256; ++g)
            acc = fmaf(bkv[256 + g], Wo[g * 256 + t], acc);
        ws[WS_BVO + t] = acc;
    }
}

// ---------------- fused layernorm + p = (LN(q)@A + pb)/16  (bf16 MFMA, bf16 out) ------
// 64 rows per block, 4 waves; wave w owns output columns [64w, 64w+64)
__global__ __launch_bounds__(256)
void ln_p_mfma(const float* __restrict__ queries, const float* __restrict__ gamma,
               const float* __restrict__ beta, float* __restrict__ ws) {
    __shared__ unsigned short qs[64][264];   // bf16 LN(q) tile; reused for p repack
    const unsigned short* Afrag = (const unsigned short*)(ws + WS_ABF);
    const float* pb = ws + WS_PB;
    unsigned short* pbf = (unsigned short*)(ws + WS_P);
    int tid = threadIdx.x, wave = tid >> 6, lane = tid & 63;
    long row0 = (long)blockIdx.x * 64;

    float4 g4 = *(const float4*)(gamma + 4 * lane);
    float4 b4 = *(const float4*)(beta + 4 * lane);
    for (int rr = 0; rr < 16; ++rr) {
        int r = wave * 16 + rr;
        float4 v = *(const float4*)(queries + (row0 + r) * 256 + 4 * lane);
        float s = v.x + v.y + v.z + v.w;
        s += __shfl_xor(s, 32); s += __shfl_xor(s, 16); s += __shfl_xor(s, 8);
        s += __shfl_xor(s, 4);  s += __shfl_xor(s, 2);  s += __shfl_xor(s, 1);
        float mu = s * 0.00390625f;
        float dx = v.x - mu, dy = v.y - mu, dz = v.z - mu, dw = v.w - mu;
        float vv = dx * dx + dy * dy + dz * dz + dw * dw;
        vv += __shfl_xor(vv, 32); vv += __shfl_xor(vv, 16); vv += __shfl_xor(vv, 8);
        vv += __shfl_xor(vv, 4);  vv += __shfl_xor(vv, 2);  vv += __shfl_xor(vv, 1);
        float rstd = rsqrtf(vv * 0.00390625f + 1e-5f);
        float qx = dx * rstd * g4.x + b4.x;
        float qy = dy * rstd * g4.y + b4.y;
        float qz = dz * rstd * g4.z + b4.z;
        float qw = dw * rstd * g4.w + b4.w;
        unsigned lo = (unsigned)f2bf(qx) | ((unsigned)f2bf(qy) << 16);
        unsigned hi = (unsigned)f2bf(qz) | ((unsigned)f2bf(qw) << 16);
        *(uint2*)&qs[r][4 * lane] = make_uint2(lo, hi);
    }
    __syncthreads();

    int r16 = lane & 15, g = lane >> 4;
    f32x4 zero = {0.f, 0.f, 0.f, 0.f};
    f32x4 acc[4][4];
    #pragma unroll
    for (int mt = 0; mt < 4; ++mt)
        #pragma unroll
        for (int nt = 0; nt < 4; ++nt) acc[mt][nt] = zero;

    #pragma unroll
    for (int ks = 0; ks < 8; ++ks) {
        short8 bfr[4], afr[4];
        #pragma unroll
        for (int nt = 0; nt < 4; ++nt)
            bfr[nt] = *(const short8*)(Afrag + (((((wave * 4 + nt) << 3) + ks) << 6) + lane) * 8);
        #pragma unroll
        for (int mt = 0; mt < 4; ++mt)
            afr[mt] = *(const short8*)(&qs[mt * 16 + r16][ks * 32 + g * 8]);
        #pragma unroll
        for (int mt = 0; mt < 4; ++mt)
            #pragma unroll
            for (int nt = 0; nt < 4; ++nt)
                acc[mt][nt] = __builtin_amdgcn_mfma_f32_16x16x32_bf16(afr[mt], bfr[nt], acc[mt][nt], 0, 0, 0);
    }
    __syncthreads();   // done reading qs (A-frags) before repacking p into it

    float pbv[4];
    #pragma unroll
    for (int nt = 0; nt < 4; ++nt) pbv[nt] = pb[wave * 64 + nt * 16 + r16];
    #pragma unroll
    for (int mt = 0; mt < 4; ++mt)
        #pragma unroll
        for (int nt = 0; nt < 4; ++nt)
            #pragma unroll
            for (int rg = 0; rg < 4; ++rg)
                qs[mt * 16 + g * 4 + rg][wave * 64 + nt * 16 + r16] =
                    f2bf((acc[mt][nt][rg] + pbv[nt]) * 0.0625f);
    __syncthreads();

    for (int rr = 0; rr < 16; ++rr) {
        int r = wave * 16 + rr;
        uint2 v = *(const uint2*)&qs[r][4 * lane];
        *(uint2*)(pbf + ((row0 + r) << 8) + 4 * lane) = v;
    }
}

// ---------------- sample + score + softmax + weighted sum (round-2 shape) -------------
// one wave per row, 4 dims/lane; p read bf16 (pre-scaled 1/16); sbar bf16 in-place
__global__ __launch_bounds__(256)
void sample_attn_bf(const float* __restrict__ coords, const int* __restrict__ vmask,
                    float* __restrict__ ws) {
    unsigned short* pbf = (unsigned short*)(ws + WS_P);
    float* suma = ws + WS_SUMA;
    const unsigned short* featbf = (const unsigned short*)(ws + WS_FEATBF);
    int tid = threadIdx.x, wave = tid >> 6, lane = tid & 63;
    long row = (long)blockIdx.x * 4 + wave;
    int b = (int)(row >> 14);
    int n = (int)(row & 16383);

    uint2 pv = ((const uint2*)(pbf + (row << 8)))[lane];
    float p0 = bf_lo(pv.x), p1 = bf_hi(pv.x), p2 = bf_lo(pv.y), p3 = bf_hi(pv.y);

    float4 sc[8];
    float score[8];
    bool vld[8];
    #pragma unroll
    for (int c = 0; c < 8; ++c) {
        long cb = ((long)(b * 8 + c) << 14) + n;
        float2 cxy = *(const float2*)(coords + 2 * cb);
        vld[c] = (vmask[cb] != 0);
        float x = (cxy.x + 1.f) * 31.5f;
        float y = (cxy.y + 1.f) * 31.5f;
        float x0f = floorf(x), y0f = floorf(y);
        float wx = x - x0f, wy = y - y0f;
        int ix0 = (int)x0f, iy0 = (int)y0f;
        int ix1 = ix0 + 1, iy1 = iy0 + 1;
        float bx0 = (ix0 >= 0 && ix0 < 64) ? 1.f : 0.f;
        float bx1 = (ix1 >= 0 && ix1 < 64) ? 1.f : 0.f;
        float by0 = (iy0 >= 0 && iy0 < 64) ? 1.f : 0.f;
        float by1 = (iy1 >= 0 && iy1 < 64) ? 1.f : 0.f;
        int cx0 = min(max(ix0, 0), 63), cx1 = min(max(ix1, 0), 63);
        int cy0 = min(max(iy0, 0), 63), cy1 = min(max(iy1, 0), 63);
        const unsigned short* fb = featbf + ((long)(b * 8 + c) << 20);
        const uint2* r00 = (const uint2*)(fb + ((cy0 * 64 + cx0) << 8)) + lane;
        const uint2* r01 = (const uint2*)(fb + ((cy0 * 64 + cx1) << 8)) + lane;
        const uint2* r10 = (const uint2*)(fb + ((cy1 * 64 + cx0) << 8)) + lane;
        const uint2* r11 = (const uint2*)(fb + ((cy1 * 64 + cx1) << 8)) + lane;
        float w00 = (1.f - wy) * (1.f - wx) * by0 * bx0;
        float w01 = (1.f - wy) * wx * by0 * bx1;
        float w10 = wy * (1.f - wx) * by1 * bx0;
        float w11 = wy * wx * by1 * bx1;
        uint2 v00 = *r00, v01 = *r01, v10 = *r10, v11 = *r11;
        float4 s;
        s.x = w00 * bf_lo(v00.x) + w01 * bf_lo(v01.x) + w10 * bf_lo(v10.x) + w11 * bf_lo(v11.x);
        s.y = w00 * bf_hi(v00.x) + w01 * bf_hi(v01.x) + w10 * bf_hi(v10.x) + w11 * bf_hi(v11.x);
        s.z = w00 * bf_lo(v00.y) + w01 * bf_lo(v01.y) + w10 * bf_lo(v10.y) + w11 * bf_lo(v11.y);
        s.w = w00 * bf_hi(v00.y) + w01 * bf_hi(v01.y) + w10 * bf_hi(v10.y) + w11 * bf_hi(v11.y);
        sc[c] = s;
        float t = s.x * p0 + s.y * p1 + s.z * p2 + s.w * p3;
        t += __shfl_xor(t, 32); t += __shfl_xor(t, 16); t += __shfl_xor(t, 8);
        t += __shfl_xor(t, 4);  t += __shfl_xor(t, 2);  t += __shfl_xor(t, 1);
        score[c] = t;            // 1/sqrt(D) pre-folded into p
    }

    float m = -INFINITY;
    #pragma unroll
    for (int c = 0; c < 8; ++c) if (vld[c]) m = fmaxf(m, score[c]);
    float4 sb = {0.f, 0.f, 0.f, 0.f};
    float sa = 0.f;
    if (m > -INFINITY) {
        float w[8], s = 0.f;
        #pragma unroll
        for (int c = 0; c < 8; ++c) { w[c] = vld[c] ? __expf(score[c] - m) : 0.f; s += w[c]; }
        float inv = 1.f / s;
        #pragma unroll
        for (int c = 0; c < 8; ++c) {
            float a = w[c] * inv;
            sb.x = fmaf(a, sc[c].x, sb.x);
            sb.y = fmaf(a, sc[c].y, sb.y);
            sb.z = fmaf(a, sc[c].z, sb.z);
            sb.w = fmaf(a, sc[c].w, sb.w);
        }
        sa = 1.f;
    }
    uint2 pk;
    pk.x = (unsigned)f2bf(sb.x) | ((unsigned)f2bf(sb.y) << 16);
    pk.y = (unsigned)f2bf(sb.z) | ((unsigned)f2bf(sb.w) << 16);
    ((uint2*)(pbf + (row << 8)))[lane] = pk;
    if (lane == 0) suma[row] = sa;
}

// ---------------- out = residual + sbar@Wvo + suma*bvo + bo  (bf16 MFMA) --------------
__global__ __launch_bounds__(256)
void final_mfma(const float* __restrict__ queries, const float* __restrict__ bo,
                const float* __restrict__ ws, float* __restrict__ out) {
    __shared__ unsigned short qs[64][264];
    __shared__ float ssu[64];
    const unsigned short* Wfrag = (const unsigned short*)(ws + WS_WVOF);
    const float* bvo = ws + WS_BVO;
    const float* suma = ws + WS_SUMA;
    const unsigned short* pbf = (const unsigned short*)(ws + WS_P);
    int tid = threadIdx.x, wave = tid >> 6, lane = tid & 63;
    long row0 = (long)blockIdx.x * 64;

    for (int rr = 0; rr < 16; ++rr) {
        int r = wave * 16 + rr;
        uint2 v = *(const uint2*)(pbf + ((row0 + r) << 8) + 4 * lane);
        *(uint2*)&qs[r][4 * lane] = v;
    }
    if (tid < 64) ssu[tid] = suma[row0 + tid];
    __syncthreads();

    int r16 = lane & 15, g = lane >> 4;
    f32x4 zero = {0.f, 0.f, 0.f, 0.f};
    f32x4 acc[4][4];
    #pragma unroll
    for (int mt = 0; mt < 4; ++mt)
        #pragma unroll
        for (int nt = 0; nt < 4; ++nt) acc[mt][nt] = zero;

    #pragma unroll
    for (int ks = 0; ks < 8; ++ks) {
        short8 bfr[4], afr[4];
        #pragma unroll
        for (int nt = 0; nt < 4; ++nt)
            bfr[nt] = *(const short8*)(Wfrag + (((((wave * 4 + nt) << 3) + ks) << 6) + lane) * 8);
        #pragma unroll
        for (int mt = 0; mt < 4; ++mt)
            afr[mt] = *(const short8*)(&qs[mt * 16 + r16][ks * 32 + g * 8]);
        #pragma unroll
        for (int mt = 0; mt < 4; ++mt)
            #pragma unroll
            for (int nt = 0; nt < 4; ++nt)
                acc[mt][nt] = __builtin_amdgcn_mfma_f32_16x16x32_bf16(afr[mt], bfr[nt], acc[mt][nt], 0, 0, 0);
    }

    float bvov[4], bov[4];
    #pragma unroll
    for (int nt = 0; nt < 4; ++nt) {
        int col = wave * 64 + nt * 16 + r16;
        bvov[nt] = bvo[col];
        bov[nt] = bo[col];
    }
    #pragma unroll
    for (int mt = 0; mt < 4; ++mt)
        #pragma unroll
        for (int nt = 0; nt < 4; ++nt)
            #pragma unroll
            for (int rg = 0; rg < 4; ++rg) {
                long row = row0 + mt * 16 + g * 4 + rg;
                int col = wave * 64 + nt * 16 + r16;
                out[row * 256 + col] = queries[row * 256 + col] + acc[mt][nt][rg]
                                     + ssu[mt * 16 + g * 4 + rg] * bvov[nt] + bov[nt];
            }
}

extern "C" void kernel_launch(void* const* d_in, const int* in_sizes, int n_in,
                              void* d_out, int out_size, void* d_ws, size_t ws_size,
                              hipStream_t stream) {
    const float* queries = (const float*)d_in[0];
    const float* feat    = (const float*)d_in[1];
    const float* coords  = (const float*)d_in[2];
    const int*   vmask   = (const int*)  d_in[3];
    const float* Wq      = (const float*)d_in[4];
    const float* bq      = (const float*)d_in[5];
    const float* Wkv     = (const float*)d_in[6];
    const float* bkv     = (const float*)d_in[7];
    const float* Wo      = (const float*)d_in[8];
    const float* bo      = (const float*)d_in[9];
    const float* gamma   = (const float*)d_in[10];
    const float* beta    = (const float*)d_in[11];
    float* out = (float*)d_out;
    float* ws  = (float*)d_ws;

    precompute_kernel<<<514 + 4096, 256, 0, stream>>>(Wq, bq, Wkv, bkv, Wo, feat, ws);
    ln_p_mfma<<<NROWS / 64, 256, 0, stream>>>(queries, gamma, beta, ws);
    sample_attn_bf<<<NROWS / 4, 256, 0, stream>>>(coords, vmask, ws);
    final_mfma<<<NROWS / 64, 256, 0, stream>>>(queries, bo, ws, out);
}